// Round 8
// baseline (541.808 us; speedup 1.0000x reference)
//
#include <hip/hip_runtime.h>

typedef __attribute__((ext_vector_type(8))) short short8;
typedef __attribute__((ext_vector_type(4))) float f32x4;

constexpr int T_STEPS = 32;
constexpr int BATCH   = 32;
constexpr int DG      = 256;
constexpr int DH      = 512;
constexpr int NHIST   = 31;
constexpr int LDA     = 520;    // padded area row (words) to spread banks
constexpr float LAMBDA_ = 0.95f;
constexpr float ETA_    = 0.5f;
constexpr float EPS_    = 1e-5f;

__device__ __forceinline__ uint bf16cvt(float f) {
  uint u = __float_as_uint(f);
  return (u + 0x7FFFu + ((u >> 16) & 1u)) >> 16;
}
__device__ __forceinline__ uint pack2(float a, float b) {
  return bf16cvt(a) | (bf16cvt(b) << 16);
}

// One cooperative kernel. Block b <-> batch b. Group = 8 blocks (b>>3).
// Block holds W_h rows [(b&7)*64, +64) as MFMA A-fragments IN REGISTERS.
// Per step: each block MFMAs its 64-row slice for all 8 batches of the group,
// publishes to HB; flag-sync; owner gathers its batch, does LN + low-rank
// fast-weight reads locally (history in LDS); publishes h bf16; flag-sync.
__global__ __launch_bounds__(512, 2) void rnn_kernel(
    const float* __restrict__ z, const float* __restrict__ Wh,
    const float* __restrict__ Wg, const float* __restrict__ bh,
    const float* __restrict__ g, const float* __restrict__ be,
    float* __restrict__ out, float* __restrict__ HB,
    ushort* __restrict__ Hpub, uint* __restrict__ flags) {
  __shared__ float  area[T_STEPS * LDA];   // ZG[t], progressively replaced by hist[t]
  __shared__ float  h_s[DH];
  __shared__ ushort hbf8[8][DH];           // h (bf16) of the 8 group batches
  __shared__ float  red1[8], red2[8];
  __shared__ float  cc[NHIST + 1];
  __shared__ float  lam_pow[NHIST];

  const int tid  = threadIdx.x;            // 0..511
  const int lane = tid & 63;
  const int wave = tid >> 6;               // 0..7
  const int c    = lane & 15;              // mfma col
  const int gq   = lane >> 4;              // mfma k-group / row-quad
  const int b    = blockIdx.x;             // batch == block
  const int grp  = b >> 3, sl = b & 7;     // group, W-row slice
  const int r    = tid;                    // owned row
  uint* gflags = flags + grp * 64;

  if (tid == 0) {
    float p = 1.f;
    for (int k = 0; k < NHIST; ++k) { lam_pow[k] = p; p *= LAMBDA_; }
  }

  // ---- Prologue A: W_h slice -> registers as A-fragments (waves 0..3) ----
  uint4 wfr[16];
  if (wave < 4) {
    const int row = sl * 64 + wave * 16 + c;
#pragma unroll
    for (int kk = 0; kk < 16; ++kk) {
      const int k0 = kk * 32 + gq * 8;
      const float4 a = *reinterpret_cast<const float4*>(Wh + (size_t)row * DH + k0);
      const float4 d = *reinterpret_cast<const float4*>(Wh + (size_t)row * DH + k0 + 4);
      wfr[kk] = make_uint4(pack2(a.x, a.y), pack2(a.z, a.w),
                           pack2(d.x, d.y), pack2(d.z, d.w));
    }
  }

  // ---- Prologue B: area[t][:] = z_b @ Wg^T  (MFMA bf16, all 8 waves) ----
#pragma unroll
  for (int mt4 = 0; mt4 < 4; ++mt4) {
    const int mt = wave * 4 + mt4;          // 32 M-tiles over DH=512
    f32x4 acc0 = {0.f,0.f,0.f,0.f}, acc1 = {0.f,0.f,0.f,0.f};
#pragma unroll
    for (int kk = 0; kk < 8; ++kk) {        // K = 256
      const int k0 = kk * 32 + gq * 8;
      const float4 a  = *reinterpret_cast<const float4*>(Wg + (size_t)(mt*16 + c) * DG + k0);
      const float4 a2 = *reinterpret_cast<const float4*>(Wg + (size_t)(mt*16 + c) * DG + k0 + 4);
      const uint4 afu = make_uint4(pack2(a.x,a.y), pack2(a.z,a.w),
                                   pack2(a2.x,a2.y), pack2(a2.z,a2.w));
      const float* zb0 = z + ((size_t)c        * BATCH + b) * DG + k0;  // t = c
      const float* zb1 = z + ((size_t)(16 + c) * BATCH + b) * DG + k0;  // t = 16+c
      const float4 b00 = *reinterpret_cast<const float4*>(zb0);
      const float4 b01 = *reinterpret_cast<const float4*>(zb0 + 4);
      const float4 b10 = *reinterpret_cast<const float4*>(zb1);
      const float4 b11 = *reinterpret_cast<const float4*>(zb1 + 4);
      const uint4 bf0 = make_uint4(pack2(b00.x,b00.y), pack2(b00.z,b00.w),
                                   pack2(b01.x,b01.y), pack2(b01.z,b01.w));
      const uint4 bf1 = make_uint4(pack2(b10.x,b10.y), pack2(b10.z,b10.w),
                                   pack2(b11.x,b11.y), pack2(b11.z,b11.w));
      acc0 = __builtin_amdgcn_mfma_f32_16x16x32_bf16(
          __builtin_bit_cast(short8, afu), __builtin_bit_cast(short8, bf0), acc0, 0,0,0);
      acc1 = __builtin_amdgcn_mfma_f32_16x16x32_bf16(
          __builtin_bit_cast(short8, afu), __builtin_bit_cast(short8, bf1), acc1, 0,0,0);
    }
    // D: col=lane&15 -> t, rows mt*16 + gq*4 + 0..3
    *reinterpret_cast<f32x4*>(&area[(size_t)c        * LDA + mt*16 + gq*4]) = acc0;
    *reinterpret_cast<f32x4*>(&area[(size_t)(16 + c) * LDA + mt*16 + gq*4]) = acc1;
  }
  __syncthreads();

  const float bh_r = bh[r], g_r = g[r], be_r = be[r];

  // LayerNorm+ReLU over 512 thread-held scalars; 2 local barriers.
  auto ln = [&](float x) -> float {
    float s1 = x, s2 = x * x;
#pragma unroll
    for (int off = 32; off; off >>= 1) {
      s1 += __shfl_xor(s1, off, 64);
      s2 += __shfl_xor(s2, off, 64);
    }
    if (lane == 0) { red1[wave] = s1; red2[wave] = s2; }
    __syncthreads();
    float a = 0.f, q = 0.f;
#pragma unroll
    for (int w2 = 0; w2 < 8; ++w2) { a += red1[w2]; q += red2[w2]; }
    const float mu = a * (1.f / DH);
    const float rs = rsqrtf(q * (1.f / DH) - mu * mu + EPS_);
    const float hv2 = fmaxf((x - mu) * rs * g_r + be_r, 0.f);
    h_s[r] = hv2;
    __syncthreads();
    return hv2;
  };

  // wave-level flag wait: lane0 polls, broadcast via shfl
  auto waitf = [&](uint* f) {
    uint v;
    do {
      v = 0;
      if (lane == 0)
        v = __hip_atomic_load(f, __ATOMIC_ACQUIRE, __HIP_MEMORY_SCOPE_AGENT);
      v = __shfl(v, 0, 64);
      if (v < 8u) __builtin_amdgcn_s_sleep(2);
    } while (v < 8u);
  };

  float hv = 0.f;
  for (int t = 0; t < T_STEPS; ++t) {
    float xb;
    if (t == 0) {
      xb = area[r] + bh_r;                 // h==0: hb = zg
    } else {
      // Phase 1: slice matvec for all 8 group batches (waves 0..3, W in regs)
      if (wave < 4) {
        f32x4 acc = {0.f,0.f,0.f,0.f};
#pragma unroll
        for (int kk = 0; kk < 16; ++kk) {
          uint4 bvu = {0u,0u,0u,0u};
          if (c < 8)
            bvu = *reinterpret_cast<const uint4*>(&hbf8[c][kk*32 + gq*8]);
          acc = __builtin_amdgcn_mfma_f32_16x16x32_bf16(
              __builtin_bit_cast(short8, wfr[kk]),
              __builtin_bit_cast(short8, bvu), acc, 0,0,0);
        }
        if (c < 8)
          *reinterpret_cast<f32x4*>(
              HB + (size_t)(grp*8 + c) * DH + sl*64 + wave*16 + gq*4) = acc;
      }
      __syncthreads();   // drains each wave's stores (vmcnt) before post
      if (tid == 0)
        __hip_atomic_fetch_add(&gflags[t*2], 1u, __ATOMIC_RELEASE,
                               __HIP_MEMORY_SCOPE_AGENT);
      waitf(&gflags[t*2]);
      xb = HB[(size_t)b * DH + r] + area[(size_t)t * LDA + r] + bh_r;
    }

    // Phase 2: h = relu(LN(hb))
    hv = ln(xb);

    // Phase 3: S_LOOP=2 fast-weight reads (A==0 at t=0 -> skip)
    if (t > 0) {
      for (int s = 0; s < 2; ++s) {
        const float4 c0 = *reinterpret_cast<const float4*>(&h_s[lane * 8]);
        const float4 c1 = *reinterpret_cast<const float4*>(&h_s[lane * 8 + 4]);
        for (int sp = wave; sp < t; sp += 8) {
          const float* hr = &area[(size_t)sp * LDA];
          const float4 a0 = *reinterpret_cast<const float4*>(&hr[lane * 8]);
          const float4 a1 = *reinterpret_cast<const float4*>(&hr[lane * 8 + 4]);
          float d = c0.x*a0.x + c0.y*a0.y + c0.z*a0.z + c0.w*a0.w
                  + c1.x*a1.x + c1.y*a1.y + c1.z*a1.z + c1.w*a1.w;
#pragma unroll
          for (int off = 32; off; off >>= 1) d += __shfl_xor(d, off, 64);
          if (lane == 0) cc[sp] = ETA_ * lam_pow[t - 1 - sp] * d;
        }
        __syncthreads();
        float ah = 0.f;
        for (int sp = 0; sp < t; ++sp) ah = fmaf(cc[sp], area[(size_t)sp * LDA + r], ah);
        hv = ln(xb + ah);
      }
    }

    // Phase 4: publish h (bf16) + append history (area[t] := h overwrites ZG[t])
    if (t < T_STEPS - 1) {
      Hpub[(size_t)b * DH + r] = (ushort)bf16cvt(hv);
      area[(size_t)t * LDA + r] = hv;
      __syncthreads();   // drain Hpub stores before post
      if (tid == 0)
        __hip_atomic_fetch_add(&gflags[t*2 + 1], 1u, __ATOMIC_RELEASE,
                               __HIP_MEMORY_SCOPE_AGENT);
      waitf(&gflags[t*2 + 1]);
      // refresh hbf8 with all 8 group batches' h
      const int cb = tid >> 6, k0 = (tid & 63) * 8;
      *reinterpret_cast<uint4*>(&hbf8[cb][k0]) =
          *reinterpret_cast<const uint4*>(&Hpub[(size_t)(grp*8 + cb) * DH + k0]);
      __syncthreads();
    }
  }

  out[(size_t)b * DH + r] = hv;
}

extern "C" void kernel_launch(void* const* d_in, const int* in_sizes, int n_in,
                              void* d_out, int out_size, void* d_ws, size_t ws_size,
                              hipStream_t stream) {
  const float* z     = (const float*)d_in[0];  // [T,B,DG]
  const float* W_h   = (const float*)d_in[1];  // [DH,DH]
  const float* W_g   = (const float*)d_in[2];  // [DH,DG]
  const float* b_h   = (const float*)d_in[3];  // [DH]
  const float* gamma = (const float*)d_in[4];  // [DH]
  const float* beta  = (const float*)d_in[5];  // [DH]
  float* out = (float*)d_out;                  // [B,DH]

  uint*   flags = (uint*)d_ws;                               // 4 grp * 64 slots
  float*  HB    = (float*)((char*)d_ws + 4096);              // [B][DH] f32
  ushort* Hpub  = (ushort*)((char*)d_ws + 4096 + 65536);     // [B][DH] bf16

  hipMemsetAsync(d_ws, 0, 4096, stream);                     // zero flags

  void* args[] = {(void*)&z, (void*)&W_h, (void*)&W_g, (void*)&b_h,
                  (void*)&gamma, (void*)&beta, (void*)&out,
                  (void*)&HB, (void*)&Hpub, (void*)&flags};
  hipLaunchCooperativeKernel((const void*)rnn_kernel, dim3(BATCH), dim3(512),
                             args, 0, stream);
}

// Round 9
// 306.042 us; speedup vs baseline: 1.7704x; 1.7704x over previous
//
#include <hip/hip_runtime.h>

typedef __attribute__((ext_vector_type(8))) short short8;
typedef __attribute__((ext_vector_type(4))) float f32x4;

constexpr int T_STEPS = 32;
constexpr int BATCH   = 32;
constexpr int DG      = 256;
constexpr int DH      = 512;
constexpr int NHIST   = 31;
constexpr int LDA     = 608;    // padded area row (words): 32*608*4 ~ 78KB -> 1 block/CU
constexpr float LAMBDA_ = 0.95f;
constexpr float ETA_    = 0.5f;
constexpr float EPS_    = 1e-5f;

__device__ __forceinline__ uint bf16cvt(float f) {
  uint u = __float_as_uint(f);
  return (u + 0x7FFFu + ((u >> 16) & 1u)) >> 16;
}
__device__ __forceinline__ uint pack2(float a, float b) {
  return bf16cvt(a) | (bf16cvt(b) << 16);
}

// pack: W_h fp32 -> bf16 MFMA A-fragment layout.
// Wp[(mt*16+kk)*64 + lane] = uint4 of 8 bf16 =
//   W[mt*16 + (lane&15)][kk*32 + (lane>>4)*8 .. +8)
__global__ __launch_bounds__(512) void pack_kernel(
    const float* __restrict__ Wh, uint4* __restrict__ Wp) {
  const int f  = blockIdx.x * 512 + threadIdx.x;   // 0..32767
  const int lf = f & 63;
  const int kk = (f >> 6) & 15;
  const int mt = f >> 10;
  const int r  = mt * 16 + (lf & 15);
  const int k0 = kk * 32 + (lf >> 4) * 8;
  const float4 a = *reinterpret_cast<const float4*>(Wh + (size_t)r * DH + k0);
  const float4 b = *reinterpret_cast<const float4*>(Wh + (size_t)r * DH + k0 + 4);
  Wp[f] = make_uint4(pack2(a.x, a.y), pack2(a.z, a.w),
                     pack2(b.x, b.y), pack2(b.z, b.w));
}

// Serial recurrence: 32 self-contained blocks x 512 threads (8 waves), one
// batch per block. 512 thr = 2 waves/EU -> 256-VGPR budget (round-8 evidence:
// compiler actually uses >64 at this size; rounds 4-7 showed 1024-thr blocks
// pin at 64 and spill any pipeline).
// Prologue: area[t][:] = z_b @ Wg^T via MFMA (ZG lives in LDS; overwritten by
// hist[t] as each step retires). Phase 1 streams packed W (512 KB bf16/step)
// with 4 independent MFMA chains/wave. A.h kept implicitly low-rank.
__global__ __launch_bounds__(512, 2) void rnn_kernel(
    const uint4* __restrict__ Wp, const float* __restrict__ z,
    const float* __restrict__ Wg, const float* __restrict__ bh,
    const float* __restrict__ g, const float* __restrict__ be,
    float* __restrict__ out) {
  __shared__ float  area[T_STEPS * LDA];   // ZG[t] -> hist[t]
  __shared__ float  part[DH];
  __shared__ float  h_s[DH];
  __shared__ ushort hbf[DH];
  __shared__ float  red1[8], red2[8];
  __shared__ float  cc[NHIST + 1];
  __shared__ float  lam_pow[NHIST];

  const int tid  = threadIdx.x;            // 0..511
  const int lane = tid & 63;
  const int wave = tid >> 6;               // 0..7
  const int c    = lane & 15;              // mfma col
  const int gq   = lane >> 4;              // mfma k-group / row-quad
  const int b    = blockIdx.x;             // batch == block
  const int r    = tid;                    // owned row

  if (tid == 0) {
    float p = 1.f;
    for (int k = 0; k < NHIST; ++k) { lam_pow[k] = p; p *= LAMBDA_; }
  }

  // ---- Prologue: area[t][:] = z_b @ Wg^T (MFMA bf16; cols = t, 2 halves) ----
#pragma unroll
  for (int mt4 = 0; mt4 < 4; ++mt4) {
    const int mt = wave * 4 + mt4;          // 32 M-tiles over DH=512
    f32x4 acc0 = {0.f,0.f,0.f,0.f}, acc1 = {0.f,0.f,0.f,0.f};
#pragma unroll
    for (int kk = 0; kk < 8; ++kk) {        // K = 256
      const int k0 = kk * 32 + gq * 8;
      const float4 a  = *reinterpret_cast<const float4*>(Wg + (size_t)(mt*16 + c) * DG + k0);
      const float4 a2 = *reinterpret_cast<const float4*>(Wg + (size_t)(mt*16 + c) * DG + k0 + 4);
      const uint4 afu = make_uint4(pack2(a.x,a.y), pack2(a.z,a.w),
                                   pack2(a2.x,a2.y), pack2(a2.z,a2.w));
      const float* zb0 = z + ((size_t)c        * BATCH + b) * DG + k0;  // t = c
      const float* zb1 = z + ((size_t)(16 + c) * BATCH + b) * DG + k0;  // t = 16+c
      const float4 b00 = *reinterpret_cast<const float4*>(zb0);
      const float4 b01 = *reinterpret_cast<const float4*>(zb0 + 4);
      const float4 b10 = *reinterpret_cast<const float4*>(zb1);
      const float4 b11 = *reinterpret_cast<const float4*>(zb1 + 4);
      const uint4 bf0 = make_uint4(pack2(b00.x,b00.y), pack2(b00.z,b00.w),
                                   pack2(b01.x,b01.y), pack2(b01.z,b01.w));
      const uint4 bf1 = make_uint4(pack2(b10.x,b10.y), pack2(b10.z,b10.w),
                                   pack2(b11.x,b11.y), pack2(b11.z,b11.w));
      acc0 = __builtin_amdgcn_mfma_f32_16x16x32_bf16(
          __builtin_bit_cast(short8, afu), __builtin_bit_cast(short8, bf0), acc0, 0,0,0);
      acc1 = __builtin_amdgcn_mfma_f32_16x16x32_bf16(
          __builtin_bit_cast(short8, afu), __builtin_bit_cast(short8, bf1), acc1, 0,0,0);
    }
    // D: col=lane&15 -> t, rows mt*16 + gq*4 + 0..3
    *reinterpret_cast<f32x4*>(&area[(size_t)c        * LDA + mt*16 + gq*4]) = acc0;
    *reinterpret_cast<f32x4*>(&area[(size_t)(16 + c) * LDA + mt*16 + gq*4]) = acc1;
  }
  __syncthreads();

  const float bh_r = bh[r], g_r = g[r], be_r = be[r];

  // LayerNorm+ReLU over 512 thread-held scalars; 2 barriers; writes h_s+hbf.
  auto ln = [&](float x) -> float {
    float s1 = x, s2 = x * x;
#pragma unroll
    for (int off = 32; off; off >>= 1) {
      s1 += __shfl_xor(s1, off, 64);
      s2 += __shfl_xor(s2, off, 64);
    }
    if (lane == 0) { red1[wave] = s1; red2[wave] = s2; }
    __syncthreads();
    float a = 0.f, q = 0.f;
#pragma unroll
    for (int w2 = 0; w2 < 8; ++w2) { a += red1[w2]; q += red2[w2]; }
    const float mu = a * (1.f / DH);
    const float rs = rsqrtf(q * (1.f / DH) - mu * mu + EPS_);
    const float hv2 = fmaxf((x - mu) * rs * g_r + be_r, 0.f);
    h_s[r] = hv2;
    hbf[r] = (ushort)bf16cvt(hv2);
    __syncthreads();
    return hv2;
  };

  float hv = 0.f;
  for (int t = 0; t < T_STEPS; ++t) {
    float xb;
    if (t == 0) {
      xb = area[r] + bh_r;                 // h==0: hb = zg
    } else {
      // Phase 1: hb = Wh.h via MFMA. Wave owns M-tiles wave*4..+3; 4
      // independent acc chains; 64 coalesced 1KB A-loads per wave.
      f32x4 acc[4] = {{0.f,0.f,0.f,0.f},{0.f,0.f,0.f,0.f},
                      {0.f,0.f,0.f,0.f},{0.f,0.f,0.f,0.f}};
#pragma unroll
      for (int kk = 0; kk < 16; ++kk) {
        uint4 bvu = {0u,0u,0u,0u};
        if (c == 0)
          bvu = *reinterpret_cast<const uint4*>(&hbf[kk*32 + gq*8]);
        const short8 bv = __builtin_bit_cast(short8, bvu);
#pragma unroll
        for (int mt4 = 0; mt4 < 4; ++mt4) {
          const int mt = wave * 4 + mt4;
          const uint4 au = Wp[(size_t)(mt*16 + kk) * 64 + lane];
          acc[mt4] = __builtin_amdgcn_mfma_f32_16x16x32_bf16(
              __builtin_bit_cast(short8, au), bv, acc[mt4], 0,0,0);
        }
      }
      if (c == 0) {
#pragma unroll
        for (int mt4 = 0; mt4 < 4; ++mt4)
          *reinterpret_cast<f32x4*>(&part[(wave*4 + mt4)*16 + gq*4]) = acc[mt4];
      }
      __syncthreads();                                   // B1
      xb = part[r] + area[(size_t)t * LDA + r] + bh_r;
    }

    // Phase 2: h = relu(LN(hb))
    hv = ln(xb);                                          // B2,B3

    // Phase 3: S_LOOP=2 fast-weight reads (A==0 at t=0 -> skip)
    if (t > 0) {
      for (int s = 0; s < 2; ++s) {
        // cc[sp] = ETA*lambda^(t-1-sp) * (hist[sp] . h)
        const float4 c0 = *reinterpret_cast<const float4*>(&h_s[lane * 8]);
        const float4 c1 = *reinterpret_cast<const float4*>(&h_s[lane * 8 + 4]);
        for (int sp = wave; sp < t; sp += 8) {
          const float* hr = &area[(size_t)sp * LDA];
          const float4 a0 = *reinterpret_cast<const float4*>(&hr[lane * 8]);
          const float4 a1 = *reinterpret_cast<const float4*>(&hr[lane * 8 + 4]);
          float d = c0.x*a0.x + c0.y*a0.y + c0.z*a0.z + c0.w*a0.w
                  + c1.x*a1.x + c1.y*a1.y + c1.z*a1.z + c1.w*a1.w;
#pragma unroll
          for (int off = 32; off; off >>= 1) d += __shfl_xor(d, off, 64);
          if (lane == 0) cc[sp] = ETA_ * lam_pow[t - 1 - sp] * d;
        }
        __syncthreads();                                  // B4
        float ah = 0.f;
        for (int sp = 0; sp < t; ++sp) ah = fmaf(cc[sp], area[(size_t)sp * LDA + r], ah);
        hv = ln(xb + ah);                                 // B5,B6
      }
    }

    // Phase 4: hist[t] := h overwrites ZG[t] (read as hist only after B1+ln
    // barriers of later steps; hbf already published inside ln)
    if (t < T_STEPS - 1) area[(size_t)t * LDA + r] = hv;
  }

  out[(size_t)b * DH + r] = hv;
}

extern "C" void kernel_launch(void* const* d_in, const int* in_sizes, int n_in,
                              void* d_out, int out_size, void* d_ws, size_t ws_size,
                              hipStream_t stream) {
  const float* z     = (const float*)d_in[0];  // [T,B,DG]
  const float* W_h   = (const float*)d_in[1];  // [DH,DH]
  const float* W_g   = (const float*)d_in[2];  // [DH,DG]
  const float* b_h   = (const float*)d_in[3];  // [DH]
  const float* gamma = (const float*)d_in[4];  // [DH]
  const float* beta  = (const float*)d_in[5];  // [DH]
  float* out = (float*)d_out;                  // [B,DH]

  uint4* Wp = (uint4*)d_ws;                    // 512 KB packed W_h

  pack_kernel<<<dim3(64), dim3(512), 0, stream>>>(W_h, Wp);
  rnn_kernel<<<dim3(BATCH), dim3(512), 0, stream>>>(Wp, z, W_g, b_h,
                                                    gamma, beta, out);
}

// Round 10
// 292.387 us; speedup vs baseline: 1.8531x; 1.0467x over previous
//
#include <hip/hip_runtime.h>

typedef __attribute__((ext_vector_type(8))) short short8;
typedef __attribute__((ext_vector_type(4))) float f32x4;

constexpr int T_STEPS = 32;
constexpr int BATCH   = 32;
constexpr int DG      = 256;
constexpr int DH      = 512;
constexpr int NHIST   = 31;
constexpr int LDA     = 544;    // padded fp32 area row (words)
constexpr int LDT     = 40;     // histT row (ushorts): 80 B, 16B-aligned
constexpr float LAMBDA_ = 0.95f;
constexpr float ETA_    = 0.5f;
constexpr float EPS_    = 1e-5f;

__device__ __forceinline__ uint bf16cvt(float f) {
  uint u = __float_as_uint(f);
  return (u + 0x7FFFu + ((u >> 16) & 1u)) >> 16;
}
__device__ __forceinline__ uint pack2(float a, float b) {
  return bf16cvt(a) | (bf16cvt(b) << 16);
}
__device__ __forceinline__ float bf2f(ushort u) {
  return __uint_as_float(((uint)u) << 16);
}

// pack: W_h fp32 -> bf16 MFMA A-fragment layout.
// Wp[(mt*16+kk)*64 + lane] = uint4 of 8 bf16 =
//   W[mt*16 + (lane&15)][kk*32 + (lane>>4)*8 .. +8)
__global__ __launch_bounds__(512) void pack_kernel(
    const float* __restrict__ Wh, uint4* __restrict__ Wp) {
  const int f  = blockIdx.x * 512 + threadIdx.x;   // 0..32767
  const int lf = f & 63;
  const int kk = (f >> 6) & 15;
  const int mt = f >> 10;
  const int r  = mt * 16 + (lf & 15);
  const int k0 = kk * 32 + (lf >> 4) * 8;
  const float4 a = *reinterpret_cast<const float4*>(Wh + (size_t)r * DH + k0);
  const float4 b = *reinterpret_cast<const float4*>(Wh + (size_t)r * DH + k0 + 4);
  Wp[f] = make_uint4(pack2(a.x, a.y), pack2(a.z, a.w),
                     pack2(b.x, b.y), pack2(b.z, b.w));
}

// Serial recurrence: 32 self-contained blocks x 512 threads, one batch each.
// K-half kk=0..7 of this block's W lives in REGISTERS (32 uint4 = 128 VGPR,
// loaded once; 512thr => 256-VGPR budget); only kk=8..15 (256 KB) streams
// from L2 per step. Ah gather reads a TRANSPOSED bf16 history row (own-thread
// row: no extra sync; 4 b128 reads instead of 31 scalar reads).
__global__ __launch_bounds__(512, 2) void rnn_kernel(
    const uint4* __restrict__ Wp, const float* __restrict__ z,
    const float* __restrict__ Wg, const float* __restrict__ bh,
    const float* __restrict__ g, const float* __restrict__ be,
    float* __restrict__ out) {
  __shared__ float  area[T_STEPS * LDA];     // ZG[t] -> hist[t]  (~70 KB)
  __shared__ ushort histT[DH][LDT];          // bf16 history, transposed (40 KB)
  __shared__ float  part[DH];
  __shared__ float  h_s[DH];
  __shared__ ushort hbf[DH];
  __shared__ float  red1[8], red2[8];
  __shared__ float  cc[NHIST + 1];
  __shared__ float  lam_pow[NHIST];

  const int tid  = threadIdx.x;            // 0..511
  const int lane = tid & 63;
  const int wave = tid >> 6;               // 0..7
  const int c    = lane & 15;              // mfma col
  const int gq   = lane >> 4;              // mfma k-group / row-quad
  const int b    = blockIdx.x;             // batch == block
  const int r    = tid;                    // owned row

  if (tid == 0) {
    float p = 1.f;
    for (int k = 0; k < NHIST; ++k) { lam_pow[k] = p; p *= LAMBDA_; }
  }
  if (tid < NHIST + 1) cc[tid] = 0.f;      // slots >= t stay 0 -> no Ah guards

  // ---- Resident W: kk=0..7 (K in [0,256)) as A-fragments, 32 uint4 ----
  uint4 wfr[4][8];
#pragma unroll
  for (int mt4 = 0; mt4 < 4; ++mt4)
#pragma unroll
    for (int kk = 0; kk < 8; ++kk)
      wfr[mt4][kk] = Wp[(size_t)((wave * 4 + mt4) * 16 + kk) * 64 + lane];

  // ---- Prologue: area[t][:] = z_b @ Wg^T (MFMA bf16; cols = t, 2 halves) ----
#pragma unroll
  for (int mt4 = 0; mt4 < 4; ++mt4) {
    const int mt = wave * 4 + mt4;          // 32 M-tiles over DH=512
    f32x4 acc0 = {0.f,0.f,0.f,0.f}, acc1 = {0.f,0.f,0.f,0.f};
#pragma unroll
    for (int kk = 0; kk < 8; ++kk) {        // K = 256
      const int k0 = kk * 32 + gq * 8;
      const float4 a  = *reinterpret_cast<const float4*>(Wg + (size_t)(mt*16 + c) * DG + k0);
      const float4 a2 = *reinterpret_cast<const float4*>(Wg + (size_t)(mt*16 + c) * DG + k0 + 4);
      const uint4 afu = make_uint4(pack2(a.x,a.y), pack2(a.z,a.w),
                                   pack2(a2.x,a2.y), pack2(a2.z,a2.w));
      const float* zb0 = z + ((size_t)c        * BATCH + b) * DG + k0;  // t = c
      const float* zb1 = z + ((size_t)(16 + c) * BATCH + b) * DG + k0;  // t = 16+c
      const float4 b00 = *reinterpret_cast<const float4*>(zb0);
      const float4 b01 = *reinterpret_cast<const float4*>(zb0 + 4);
      const float4 b10 = *reinterpret_cast<const float4*>(zb1);
      const float4 b11 = *reinterpret_cast<const float4*>(zb1 + 4);
      const uint4 bf0 = make_uint4(pack2(b00.x,b00.y), pack2(b00.z,b00.w),
                                   pack2(b01.x,b01.y), pack2(b01.z,b01.w));
      const uint4 bf1 = make_uint4(pack2(b10.x,b10.y), pack2(b10.z,b10.w),
                                   pack2(b11.x,b11.y), pack2(b11.z,b11.w));
      acc0 = __builtin_amdgcn_mfma_f32_16x16x32_bf16(
          __builtin_bit_cast(short8, afu), __builtin_bit_cast(short8, bf0), acc0, 0,0,0);
      acc1 = __builtin_amdgcn_mfma_f32_16x16x32_bf16(
          __builtin_bit_cast(short8, afu), __builtin_bit_cast(short8, bf1), acc1, 0,0,0);
    }
    // D: col=lane&15 -> t, rows mt*16 + gq*4 + 0..3
    *reinterpret_cast<f32x4*>(&area[(size_t)c        * LDA + mt*16 + gq*4]) = acc0;
    *reinterpret_cast<f32x4*>(&area[(size_t)(16 + c) * LDA + mt*16 + gq*4]) = acc1;
  }
  __syncthreads();

  const float bh_r = bh[r], g_r = g[r], be_r = be[r];

  // LayerNorm+ReLU over 512 thread-held scalars; 2 barriers; writes h_s+hbf.
  auto ln = [&](float x) -> float {
    float s1 = x, s2 = x * x;
#pragma unroll
    for (int off = 32; off; off >>= 1) {
      s1 += __shfl_xor(s1, off, 64);
      s2 += __shfl_xor(s2, off, 64);
    }
    if (lane == 0) { red1[wave] = s1; red2[wave] = s2; }
    __syncthreads();
    float a = 0.f, q = 0.f;
#pragma unroll
    for (int w2 = 0; w2 < 8; ++w2) { a += red1[w2]; q += red2[w2]; }
    const float mu = a * (1.f / DH);
    const float rs = rsqrtf(q * (1.f / DH) - mu * mu + EPS_);
    const float hv2 = fmaxf((x - mu) * rs * g_r + be_r, 0.f);
    h_s[r] = hv2;
    hbf[r] = (ushort)bf16cvt(hv2);
    __syncthreads();
    return hv2;
  };

  float hv = 0.f;
  for (int t = 0; t < T_STEPS; ++t) {
    float xb;
    if (t == 0) {
      xb = area[r] + bh_r;                 // h==0: hb = zg
    } else {
      // Phase 1: hb = Wh.h via MFMA. Resident half first (pure compute);
      // streamed half's loads hoist above it for latency hiding.
      f32x4 acc[4] = {{0.f,0.f,0.f,0.f},{0.f,0.f,0.f,0.f},
                      {0.f,0.f,0.f,0.f},{0.f,0.f,0.f,0.f}};
#pragma unroll
      for (int kk = 0; kk < 8; ++kk) {
        uint4 bvu = {0u,0u,0u,0u};
        if (c == 0)
          bvu = *reinterpret_cast<const uint4*>(&hbf[kk*32 + gq*8]);
        const short8 bv = __builtin_bit_cast(short8, bvu);
#pragma unroll
        for (int mt4 = 0; mt4 < 4; ++mt4)
          acc[mt4] = __builtin_amdgcn_mfma_f32_16x16x32_bf16(
              __builtin_bit_cast(short8, wfr[mt4][kk]), bv, acc[mt4], 0,0,0);
      }
#pragma unroll
      for (int kk = 8; kk < 16; ++kk) {
        uint4 bvu = {0u,0u,0u,0u};
        if (c == 0)
          bvu = *reinterpret_cast<const uint4*>(&hbf[kk*32 + gq*8]);
        const short8 bv = __builtin_bit_cast(short8, bvu);
#pragma unroll
        for (int mt4 = 0; mt4 < 4; ++mt4) {
          const uint4 au = Wp[(size_t)((wave*4 + mt4)*16 + kk) * 64 + lane];
          acc[mt4] = __builtin_amdgcn_mfma_f32_16x16x32_bf16(
              __builtin_bit_cast(short8, au), bv, acc[mt4], 0,0,0);
        }
      }
      if (c == 0) {
#pragma unroll
        for (int mt4 = 0; mt4 < 4; ++mt4)
          *reinterpret_cast<f32x4*>(&part[(wave*4 + mt4)*16 + gq*4]) = acc[mt4];
      }
      __syncthreads();                                   // B1
      xb = part[r] + area[(size_t)t * LDA + r] + bh_r;
    }

    // Phase 2: h = relu(LN(hb))
    hv = ln(xb);                                          // B2,B3

    // Phase 3: S_LOOP=2 fast-weight reads (A==0 at t=0 -> skip)
    if (t > 0) {
      for (int s = 0; s < 2; ++s) {
        // cc[sp] = ETA*lambda^(t-1-sp) * (hist[sp] . h)
        const float4 c0 = *reinterpret_cast<const float4*>(&h_s[lane * 8]);
        const float4 c1 = *reinterpret_cast<const float4*>(&h_s[lane * 8 + 4]);
        for (int sp = wave; sp < t; sp += 8) {
          const float* hr = &area[(size_t)sp * LDA];
          const float4 a0 = *reinterpret_cast<const float4*>(&hr[lane * 8]);
          const float4 a1 = *reinterpret_cast<const float4*>(&hr[lane * 8 + 4]);
          float d = c0.x*a0.x + c0.y*a0.y + c0.z*a0.z + c0.w*a0.w
                  + c1.x*a1.x + c1.y*a1.y + c1.z*a1.z + c1.w*a1.w;
#pragma unroll
          for (int off = 32; off; off >>= 1) d += __shfl_xor(d, off, 64);
          if (lane == 0) cc[sp] = ETA_ * lam_pow[t - 1 - sp] * d;
        }
        __syncthreads();                                  // B4
        // Ah from own-thread transposed bf16 history row: 4 x b128 + 32 fmaf
        float ah = 0.f;
#pragma unroll
        for (int q8 = 0; q8 < 4; ++q8) {
          const uint4 hw = *reinterpret_cast<const uint4*>(&histT[r][q8 * 8]);
          const uint w0 = hw.x, w1 = hw.y, w2 = hw.z, w3 = hw.w;
          ah = fmaf(cc[q8*8+0], __uint_as_float(w0 << 16),          ah);
          ah = fmaf(cc[q8*8+1], __uint_as_float(w0 & 0xFFFF0000u),  ah);
          ah = fmaf(cc[q8*8+2], __uint_as_float(w1 << 16),          ah);
          ah = fmaf(cc[q8*8+3], __uint_as_float(w1 & 0xFFFF0000u),  ah);
          ah = fmaf(cc[q8*8+4], __uint_as_float(w2 << 16),          ah);
          ah = fmaf(cc[q8*8+5], __uint_as_float(w2 & 0xFFFF0000u),  ah);
          ah = fmaf(cc[q8*8+6], __uint_as_float(w3 << 16),          ah);
          ah = fmaf(cc[q8*8+7], __uint_as_float(w3 & 0xFFFF0000u),  ah);
        }
        hv = ln(xb + ah);                                 // B5,B6
      }
    }

    // Phase 4: hist[t] := h (area row for dots; own histT row for Ah —
    // same-thread write/read, needs no barrier)
    if (t < T_STEPS - 1) {
      area[(size_t)t * LDA + r] = hv;
      histT[r][t] = (ushort)bf16cvt(hv);
    }
  }

  out[(size_t)b * DH + r] = hv;
}

extern "C" void kernel_launch(void* const* d_in, const int* in_sizes, int n_in,
                              void* d_out, int out_size, void* d_ws, size_t ws_size,
                              hipStream_t stream) {
  const float* z     = (const float*)d_in[0];  // [T,B,DG]
  const float* W_h   = (const float*)d_in[1];  // [DH,DH]
  const float* W_g   = (const float*)d_in[2];  // [DH,DG]
  const float* b_h   = (const float*)d_in[3];  // [DH]
  const float* gamma = (const float*)d_in[4];  // [DH]
  const float* beta  = (const float*)d_in[5];  // [DH]
  float* out = (float*)d_out;                  // [B,DH]

  uint4* Wp = (uint4*)d_ws;                    // 512 KB packed W_h

  pack_kernel<<<dim3(64), dim3(512), 0, stream>>>(W_h, Wp);
  rnn_kernel<<<dim3(BATCH), dim3(512), 0, stream>>>(Wp, z, W_g, b_h,
                                                    gamma, beta, out);
}

// Round 13
// 292.253 us; speedup vs baseline: 1.8539x; 1.0005x over previous
//
#include <hip/hip_runtime.h>

typedef __attribute__((ext_vector_type(8))) short short8;
typedef __attribute__((ext_vector_type(4))) float f32x4;

constexpr int T_STEPS = 32;
constexpr int BATCH   = 32;
constexpr int DG      = 256;
constexpr int DH      = 512;
constexpr int NHIST   = 31;
constexpr int LDA     = 544;    // padded fp32 area row (words)
constexpr int LDT     = 40;     // histT row (ushorts): 80 B, 16B-aligned
constexpr float LAMBDA_ = 0.95f;
constexpr float ETA_    = 0.5f;
constexpr float EPS_    = 1e-5f;

__device__ __forceinline__ uint bf16cvt(float f) {
  uint u = __float_as_uint(f);
  return (u + 0x7FFFu + ((u >> 16) & 1u)) >> 16;
}
__device__ __forceinline__ uint pack2(float a, float b) {
  return bf16cvt(a) | (bf16cvt(b) << 16);
}

// pack: W_h fp32 -> bf16 MFMA A-fragment layout.
// Wp[(mt*16+kk)*64 + lane] = uint4 of 8 bf16 =
//   W[mt*16 + (lane&15)][kk*32 + (lane>>4)*8 .. +8)
__global__ __launch_bounds__(512) void pack_kernel(
    const float* __restrict__ Wh, uint4* __restrict__ Wp) {
  const int f  = blockIdx.x * 512 + threadIdx.x;   // 0..32767
  const int lf = f & 63;
  const int kk = (f >> 6) & 15;
  const int mt = f >> 10;
  const int r  = mt * 16 + (lf & 15);
  const int k0 = kk * 32 + (lf >> 4) * 8;
  const float4 a = *reinterpret_cast<const float4*>(Wh + (size_t)r * DH + k0);
  const float4 b = *reinterpret_cast<const float4*>(Wh + (size_t)r * DH + k0 + 4);
  Wp[f] = make_uint4(pack2(a.x, a.y), pack2(a.z, a.w),
                     pack2(b.x, b.y), pack2(b.z, b.w));
}

// Serial recurrence: 32 self-contained blocks x 512 threads, one batch each.
// Round-10 structure verbatim (last passing version). Change vs round 10:
// amdgpu_waves_per_eu(2,2) tells the allocator the truth (LDS pins us to
// 1 block/CU = 2 waves/EU), unlocking the 256-VGPR budget so it can keep
// more W loads in flight (or the wfr half resident) WITHOUT inline-asm
// coercion (rounds 11/12 post-mortem: empty-asm register pins miscompile).
__global__ __launch_bounds__(512, 2)
__attribute__((amdgpu_waves_per_eu(2, 2)))
void rnn_kernel(
    const uint4* __restrict__ Wp, const float* __restrict__ z,
    const float* __restrict__ Wg, const float* __restrict__ bh,
    const float* __restrict__ g, const float* __restrict__ be,
    float* __restrict__ out) {
  __shared__ float  area[T_STEPS * LDA];     // ZG[t] -> hist[t]  (~70 KB)
  __shared__ ushort histT[DH][LDT];          // bf16 history, transposed (40 KB)
  __shared__ float  part[DH];
  __shared__ float  h_s[DH];
  __shared__ ushort hbf[DH];
  __shared__ float  red1[8], red2[8];
  __shared__ float  cc[NHIST + 1];
  __shared__ float  lam_pow[NHIST];

  const int tid  = threadIdx.x;            // 0..511
  const int lane = tid & 63;
  const int wave = tid >> 6;               // 0..7
  const int c    = lane & 15;              // mfma col
  const int gq   = lane >> 4;              // mfma k-group / row-quad
  const int b    = blockIdx.x;             // batch == block
  const int r    = tid;                    // owned row

  if (tid == 0) {
    float p = 1.f;
    for (int k = 0; k < NHIST; ++k) { lam_pow[k] = p; p *= LAMBDA_; }
  }
  if (tid < NHIST + 1) cc[tid] = 0.f;      // slots >= t stay 0 -> no Ah guards
  // Zero own histT row (own-thread write/read -> no barrier needed). Kills
  // the latent 0*garbage=NaN hazard in the Ah gather for sp >= t.
  {
    uint4 zz = make_uint4(0u, 0u, 0u, 0u);
#pragma unroll
    for (int i = 0; i < 5; ++i)
      reinterpret_cast<uint4*>(&histT[r][0])[i] = zz;
  }

  // ---- Resident-candidate W: kk=0..7 (K in [0,256)) as A-fragments ----
  uint4 wfr[4][8];
#pragma unroll
  for (int mt4 = 0; mt4 < 4; ++mt4)
#pragma unroll
    for (int kk = 0; kk < 8; ++kk)
      wfr[mt4][kk] = Wp[(size_t)((wave * 4 + mt4) * 16 + kk) * 64 + lane];

  // ---- Prologue: area[t][:] = z_b @ Wg^T (MFMA bf16; cols = t, 2 halves) ----
#pragma unroll
  for (int mt4 = 0; mt4 < 4; ++mt4) {
    const int mt = wave * 4 + mt4;          // 32 M-tiles over DH=512
    f32x4 acc0 = {0.f,0.f,0.f,0.f}, acc1 = {0.f,0.f,0.f,0.f};
#pragma unroll
    for (int kk = 0; kk < 8; ++kk) {        // K = 256
      const int k0 = kk * 32 + gq * 8;
      const float4 a  = *reinterpret_cast<const float4*>(Wg + (size_t)(mt*16 + c) * DG + k0);
      const float4 a2 = *reinterpret_cast<const float4*>(Wg + (size_t)(mt*16 + c) * DG + k0 + 4);
      const uint4 afu = make_uint4(pack2(a.x,a.y), pack2(a.z,a.w),
                                   pack2(a2.x,a2.y), pack2(a2.z,a2.w));
      const float* zb0 = z + ((size_t)c        * BATCH + b) * DG + k0;  // t = c
      const float* zb1 = z + ((size_t)(16 + c) * BATCH + b) * DG + k0;  // t = 16+c
      const float4 b00 = *reinterpret_cast<const float4*>(zb0);
      const float4 b01 = *reinterpret_cast<const float4*>(zb0 + 4);
      const float4 b10 = *reinterpret_cast<const float4*>(zb1);
      const float4 b11 = *reinterpret_cast<const float4*>(zb1 + 4);
      const uint4 bf0 = make_uint4(pack2(b00.x,b00.y), pack2(b00.z,b00.w),
                                   pack2(b01.x,b01.y), pack2(b01.z,b01.w));
      const uint4 bf1 = make_uint4(pack2(b10.x,b10.y), pack2(b10.z,b10.w),
                                   pack2(b11.x,b11.y), pack2(b11.z,b11.w));
      acc0 = __builtin_amdgcn_mfma_f32_16x16x32_bf16(
          __builtin_bit_cast(short8, afu), __builtin_bit_cast(short8, bf0), acc0, 0,0,0);
      acc1 = __builtin_amdgcn_mfma_f32_16x16x32_bf16(
          __builtin_bit_cast(short8, afu), __builtin_bit_cast(short8, bf1), acc1, 0,0,0);
    }
    // D: col=lane&15 -> t, rows mt*16 + gq*4 + 0..3
    *reinterpret_cast<f32x4*>(&area[(size_t)c        * LDA + mt*16 + gq*4]) = acc0;
    *reinterpret_cast<f32x4*>(&area[(size_t)(16 + c) * LDA + mt*16 + gq*4]) = acc1;
  }
  __syncthreads();

  const float bh_r = bh[r], g_r = g[r], be_r = be[r];

  // LayerNorm+ReLU over 512 thread-held scalars; 2 barriers; writes h_s+hbf.
  auto ln = [&](float x) -> float {
    float s1 = x, s2 = x * x;
#pragma unroll
    for (int off = 32; off; off >>= 1) {
      s1 += __shfl_xor(s1, off, 64);
      s2 += __shfl_xor(s2, off, 64);
    }
    if (lane == 0) { red1[wave] = s1; red2[wave] = s2; }
    __syncthreads();
    float a = 0.f, q = 0.f;
#pragma unroll
    for (int w2 = 0; w2 < 8; ++w2) { a += red1[w2]; q += red2[w2]; }
    const float mu = a * (1.f / DH);
    const float rs = rsqrtf(q * (1.f / DH) - mu * mu + EPS_);
    const float hv2 = fmaxf((x - mu) * rs * g_r + be_r, 0.f);
    h_s[r] = hv2;
    hbf[r] = (ushort)bf16cvt(hv2);
    __syncthreads();
    return hv2;
  };

  float hv = 0.f;
  for (int t = 0; t < T_STEPS; ++t) {
    float xb;
    if (t == 0) {
      xb = area[r] + bh_r;                 // h==0: hb = zg
    } else {
      // Phase 1: hb = Wh.h via MFMA. kk=0..7 from wfr (compiler may keep
      // resident with the 256-VGPR budget); kk=8..15 streamed from L2.
      f32x4 acc[4] = {{0.f,0.f,0.f,0.f},{0.f,0.f,0.f,0.f},
                      {0.f,0.f,0.f,0.f},{0.f,0.f,0.f,0.f}};
#pragma unroll
      for (int kk = 0; kk < 8; ++kk) {
        uint4 bvu = {0u,0u,0u,0u};
        if (c == 0)
          bvu = *reinterpret_cast<const uint4*>(&hbf[kk*32 + gq*8]);
        const short8 bv = __builtin_bit_cast(short8, bvu);
#pragma unroll
        for (int mt4 = 0; mt4 < 4; ++mt4)
          acc[mt4] = __builtin_amdgcn_mfma_f32_16x16x32_bf16(
              __builtin_bit_cast(short8, wfr[mt4][kk]), bv, acc[mt4], 0,0,0);
      }
#pragma unroll
      for (int kk = 8; kk < 16; ++kk) {
        uint4 bvu = {0u,0u,0u,0u};
        if (c == 0)
          bvu = *reinterpret_cast<const uint4*>(&hbf[kk*32 + gq*8]);
        const short8 bv = __builtin_bit_cast(short8, bvu);
#pragma unroll
        for (int mt4 = 0; mt4 < 4; ++mt4) {
          const uint4 au = Wp[(size_t)((wave*4 + mt4)*16 + kk) * 64 + lane];
          acc[mt4] = __builtin_amdgcn_mfma_f32_16x16x32_bf16(
              __builtin_bit_cast(short8, au), bv, acc[mt4], 0,0,0);
        }
      }
      if (c == 0) {
#pragma unroll
        for (int mt4 = 0; mt4 < 4; ++mt4)
          *reinterpret_cast<f32x4*>(&part[(wave*4 + mt4)*16 + gq*4]) = acc[mt4];
      }
      __syncthreads();                                   // B1
      xb = part[r] + area[(size_t)t * LDA + r] + bh_r;
    }

    // Phase 2: h = relu(LN(hb))
    hv = ln(xb);                                          // B2,B3

    // Phase 3: S_LOOP=2 fast-weight reads (A==0 at t=0 -> skip)
    if (t > 0) {
      for (int s = 0; s < 2; ++s) {
        // cc[sp] = ETA*lambda^(t-1-sp) * (hist[sp] . h)
        const float4 c0 = *reinterpret_cast<const float4*>(&h_s[lane * 8]);
        const float4 c1 = *reinterpret_cast<const float4*>(&h_s[lane * 8 + 4]);
        for (int sp = wave; sp < t; sp += 8) {
          const float* hr = &area[(size_t)sp * LDA];
          const float4 a0 = *reinterpret_cast<const float4*>(&hr[lane * 8]);
          const float4 a1 = *reinterpret_cast<const float4*>(&hr[lane * 8 + 4]);
          float d = c0.x*a0.x + c0.y*a0.y + c0.z*a0.z + c0.w*a0.w
                  + c1.x*a1.x + c1.y*a1.y + c1.z*a1.z + c1.w*a1.w;
#pragma unroll
          for (int off = 32; off; off >>= 1) d += __shfl_xor(d, off, 64);
          if (lane == 0) cc[sp] = ETA_ * lam_pow[t - 1 - sp] * d;
        }
        __syncthreads();                                  // B4
        // Ah from own-thread transposed bf16 history row: 4 x b128 + 32 fmaf
        float ah = 0.f;
#pragma unroll
        for (int q8 = 0; q8 < 4; ++q8) {
          const uint4 hw = *reinterpret_cast<const uint4*>(&histT[r][q8 * 8]);
          const uint w0 = hw.x, w1 = hw.y, w2 = hw.z, w3 = hw.w;
          ah = fmaf(cc[q8*8+0], __uint_as_float(w0 << 16),          ah);
          ah = fmaf(cc[q8*8+1], __uint_as_float(w0 & 0xFFFF0000u),  ah);
          ah = fmaf(cc[q8*8+2], __uint_as_float(w1 << 16),          ah);
          ah = fmaf(cc[q8*8+3], __uint_as_float(w1 & 0xFFFF0000u),  ah);
          ah = fmaf(cc[q8*8+4], __uint_as_float(w2 << 16),          ah);
          ah = fmaf(cc[q8*8+5], __uint_as_float(w2 & 0xFFFF0000u),  ah);
          ah = fmaf(cc[q8*8+6], __uint_as_float(w3 << 16),          ah);
          ah = fmaf(cc[q8*8+7], __uint_as_float(w3 & 0xFFFF0000u),  ah);
        }
        hv = ln(xb + ah);                                 // B5,B6
      }
    }

    // Phase 4: hist[t] := h (area row for dots; own histT row for Ah —
    // same-thread write/read, needs no barrier)
    if (t < T_STEPS - 1) {
      area[(size_t)t * LDA + r] = hv;
      histT[r][t] = (ushort)bf16cvt(hv);
    }
  }

  out[(size_t)b * DH + r] = hv;
}

extern "C" void kernel_launch(void* const* d_in, const int* in_sizes, int n_in,
                              void* d_out, int out_size, void* d_ws, size_t ws_size,
                              hipStream_t stream) {
  const float* z     = (const float*)d_in[0];  // [T,B,DG]
  const float* W_h   = (const float*)d_in[1];  // [DH,DH]
  const float* W_g   = (const float*)d_in[2];  // [DH,DG]
  const float* b_h   = (const float*)d_in[3];  // [DH]
  const float* gamma = (const float*)d_in[4];  // [DH]
  const float* beta  = (const float*)d_in[5];  // [DH]
  float* out = (float*)d_out;                  // [B,DH]

  uint4* Wp = (uint4*)d_ws;                    // 512 KB packed W_h

  pack_kernel<<<dim3(64), dim3(512), 0, stream>>>(W_h, Wp);
  rnn_kernel<<<dim3(BATCH), dim3(512), 0, stream>>>(Wp, z, W_g, b_h,
                                                    gamma, beta, out);
}